// Round 6
// baseline (1332.701 us; speedup 1.0000x reference)
//
#include <hip/hip_runtime.h>

// Seq2Seq: enc-LSTM -> dec-LSTM -> vocab projection.  B=32 S=T=128 E=128 H=256 V=32000.
//
// Structure:
//  prep_kernel : pack Whh_{enc,dec} to f16x2 [phase][k-dword][gate], convert W_out to bf16.
//  xg_kernel   : xg[p,b,t,g] = emb[token] . Wih[g,:]  (fp32 tiled GEMM w/ gather)
//  lstm_kernel : 1 WG/batch, 1024 thr. Thread t -> unit u=t>>2, gate qc=t&3 (row g=qc*256+u).
//                Weights: 92 k-dwords reg/AGPR + 36 k-dwords LDS (round-1 allocation).
//                Post-dot: in-quad shfl_xor combine gives every lane (i,f,g,o); all lanes
//                update c/h redundantly -> ONE barrier per step.
//                h2 is DOUBLE-BUFFERED (read s&1, write (s&1)^1): round-5's single-buffer
//                version raced (fast wave's h2 write vs slow wave's same-step dot read,
//                absmax 2.5e-2). Write-to-other-buffer makes the 1-barrier schedule legal.
//  proj_kernel : N-strip persistent (500 WGs x 64 vocab rows), B-frags hoisted to regs,
//                double-buffered A staging. Epilogue through LDS Ol[32][66]: wave-stores
//                are 16 lanes x float4 = 256 B contiguous (full lines). Rounds 0/1/4: the
//                per-lane-dword epilogue (4 scattered 64 B segments/wave) pinned proj at
//                ~0.9 TB/s write BW (~580 us, identical across two different pipelines).
//
// Workspace layout (57,344,000 B):
//   xg     f32 [2*32*128][1024]                     33,554,432
//   WhhP   u32 [2][128][1024]   (f16x2 pairs)        1,048,576
//   WoutB  bf16[32000][256]                         16,384,000
//   decO   bf16[4096][256]                           2,097,152
//   (unused)                                         4,259,840

typedef _Float16 half2v __attribute__((ext_vector_type(2)));
typedef short bf16x8 __attribute__((ext_vector_type(8)));
typedef float f32x4 __attribute__((ext_vector_type(4)));

__device__ __forceinline__ unsigned short f2h_bits(float f) {
  _Float16 h = (_Float16)f;
  return __builtin_bit_cast(unsigned short, h);
}

__device__ __forceinline__ unsigned short f2bf_bits(float f) {
  unsigned u = __builtin_bit_cast(unsigned, f);
  u += 0x7fffu + ((u >> 16) & 1u);
  return (unsigned short)(u >> 16);
}

__device__ __forceinline__ float fdot2u(unsigned wu, unsigned hu, float acc) {
#if defined(__has_builtin) && __has_builtin(__builtin_amdgcn_fdot2)
  return __builtin_amdgcn_fdot2(__builtin_bit_cast(half2v, wu),
                                __builtin_bit_cast(half2v, hu), acc, false);
#else
  half2v a = __builtin_bit_cast(half2v, wu);
  half2v b = __builtin_bit_cast(half2v, hu);
  return acc + (float)a[0] * (float)b[0] + (float)a[1] * (float)b[1];
#endif
}

__device__ __forceinline__ float tanh_fast(float x) {
  float e = __expf(2.f * x);
  return 1.f - 2.f / (e + 1.f);
}

__device__ __forceinline__ void gload_lds16(const void* g, void* l) {
#if defined(__has_builtin) && __has_builtin(__builtin_amdgcn_global_load_lds)
  __builtin_amdgcn_global_load_lds(
      (const __attribute__((address_space(1))) void*)g,
      (__attribute__((address_space(3))) void*)l, 16, 0, 0);
#else
  *(uint4*)l = *(const uint4*)g;
#endif
}

// ---------------------------------------------------------------- prep ----
__global__ void prep_kernel(const float* __restrict__ WhhE, const float* __restrict__ WhhD,
                            const float* __restrict__ Wout,
                            unsigned* __restrict__ WhhP, unsigned short* __restrict__ WoutB) {
  int i = blockIdx.x * blockDim.x + threadIdx.x;
  int stride = gridDim.x * blockDim.x;
  // Whh pack: layout [p][d][g], d = k-pair dword 0..127, g = gate row 0..1023
  for (int idx = i; idx < 262144; idx += stride) {
    int p = idx >> 17;
    int rem = idx & 131071;
    int d = rem >> 10;
    int g = rem & 1023;
    const float* W = p ? WhhD : WhhE;
    float a = W[g * 256 + 2 * d];
    float b = W[g * 256 + 2 * d + 1];
    WhhP[idx] = (unsigned)f2h_bits(a) | ((unsigned)f2h_bits(b) << 16);
  }
  for (int idx = i; idx < 8192000; idx += stride) {
    WoutB[idx] = f2bf_bits(Wout[idx]);
  }
}

// ------------------------------------------------------------------ xg ----
// xg[m][n] = sum_e emb[tok(m)][e] * Wih[n][e],  m = p*4096 + b*128 + t (8192 rows), n = 0..1023
__global__ __launch_bounds__(256, 2) void xg_kernel(
    const int* __restrict__ x, const int* __restrict__ y,
    const float* __restrict__ enc_emb, const float* __restrict__ dec_emb,
    const float* __restrict__ Wih_enc, const float* __restrict__ Wih_dec,
    float* __restrict__ xg) {
  __shared__ float Al[64][132];
  __shared__ float Bl[64][132];
  __shared__ int tok[64];
  const int nb = blockIdx.x;     // 0..15  (n tile)
  const int mbb = blockIdx.y;    // 0..127 (m tile)
  const int m0 = mbb * 64;
  const int p = mbb >> 6;
  const int tid = threadIdx.x;

  if (tid < 64) {
    int mloc = (m0 + tid) & 4095;  // index into x/y flat [32*128]
    tok[tid] = p ? y[mloc] : x[mloc];
  }
  __syncthreads();

  const float* emb = p ? dec_emb : enc_emb;
  const float* Wih = p ? Wih_dec : Wih_enc;
  {
    int ri = tid & 63, seg = tid >> 6;  // 64 rows x 4 segments of 32 floats
    const float* er = emb + (size_t)tok[ri] * 128 + seg * 32;
    const float* wr = Wih + (size_t)(nb * 64 + ri) * 128 + seg * 32;
#pragma unroll
    for (int c = 0; c < 8; ++c) {
      *(float4*)&Al[ri][seg * 32 + c * 4] = *(const float4*)&er[c * 4];
      *(float4*)&Bl[ri][seg * 32 + c * 4] = *(const float4*)&wr[c * 4];
    }
  }
  __syncthreads();

  const int tx = tid & 15, ty = tid >> 4;
  float acc[4][4];
#pragma unroll
  for (int mm = 0; mm < 4; ++mm)
#pragma unroll
    for (int nn = 0; nn < 4; ++nn) acc[mm][nn] = 0.f;

  for (int k4 = 0; k4 < 32; ++k4) {
    float4 av[4], bv[4];
#pragma unroll
    for (int mm = 0; mm < 4; ++mm) av[mm] = *(const float4*)&Al[mm * 16 + ty][k4 * 4];
#pragma unroll
    for (int nn = 0; nn < 4; ++nn) bv[nn] = *(const float4*)&Bl[nn * 16 + tx][k4 * 4];
#pragma unroll
    for (int mm = 0; mm < 4; ++mm)
#pragma unroll
      for (int nn = 0; nn < 4; ++nn) {
        acc[mm][nn] = fmaf(av[mm].x, bv[nn].x, acc[mm][nn]);
        acc[mm][nn] = fmaf(av[mm].y, bv[nn].y, acc[mm][nn]);
        acc[mm][nn] = fmaf(av[mm].z, bv[nn].z, acc[mm][nn]);
        acc[mm][nn] = fmaf(av[mm].w, bv[nn].w, acc[mm][nn]);
      }
  }
#pragma unroll
  for (int mm = 0; mm < 4; ++mm)
#pragma unroll
    for (int nn = 0; nn < 4; ++nn)
      xg[(size_t)(m0 + mm * 16 + ty) * 1024 + nb * 64 + nn * 16 + tx] = acc[mm][nn];
}

// ---------------------------------------------------------------- lstm ----
// One WG per batch, 1024 threads. Thread t: unit u=t>>2, gate class qc=t&3,
// gate row g=qc*256+u. Dot structure identical to round-1 (92 reg dwords + 36 LDS
// dwords, WL thread-indexed). Post-dot: in-quad shfl combine, all lanes update c/h
// (replicated), lane 8k packs h2 pair into the OTHER h2 buffer -> single barrier/step.
__global__ __launch_bounds__(1024, 1) void lstm_kernel(
    const float* __restrict__ xg, const unsigned* __restrict__ WhhP,
    const float* __restrict__ bih_enc, const float* __restrict__ bhh_enc,
    const float* __restrict__ bih_dec, const float* __restrict__ bhh_dec,
    unsigned short* __restrict__ decO) {   // bf16 [4096][256]
  const int b = blockIdx.x;   // batch 0..31
  const int t = threadIdx.x;  // 0..1023
  const int qc = t & 3;       // gate class 0..3 (i,f,g,o) within quad
  const int u = t >> 2;       // unit 0..255
  const int g = (qc << 8) + u;  // gate row

  __shared__ __align__(16) unsigned h2[2][128];  // double-buffered h as f16x2 pairs
  __shared__ unsigned WL[18 * 2048];             // [dp][t][2] : k-pairs 92..127, 147,456 B

  if (t < 128) h2[0][t] = 0u;  // s=0 reads buffer 0; buffer 1 is written before s=1 reads it
  float c_r = 0.f;  // cell state, replicated across the 4 lanes of each quad
  __syncthreads();

  unsigned wqd[92];  // register-resident f16x2 weight row, k-pairs 0..91
  float bias_g = 0.f;
  const float s_act = (qc == 2) ? 2.f : 1.f;  // tanh = 2*sigmoid(2x)-1
  const float o_act = 1.f - s_act;

  // prefetch xg for s=0
  float xgv_n = xg[(size_t)(b << 7) * 1024 + g];

  for (int s = 0; s < 256; ++s) {
    const int p = s >> 7;
    const int tt = s & 127;
    const int rb = s & 1;  // h2 read buffer; write goes to rb^1

    if (tt == 0) {  // phase start: (re)load weights + bias
      const unsigned* base = WhhP + (p << 17);
#pragma unroll
      for (int d = 0; d < 92; ++d) wqd[d] = base[(d << 10) + g];
      // LDS slice: thread-private column, b64-pair layout [dp][t][2] (t-indexed)
#pragma unroll
      for (int dd = 0; dd < 36; ++dd)
        WL[((dd >> 1) << 11) + (t << 1) + (dd & 1)] = base[((92 + dd) << 10) + g];
      bias_g = p ? (bih_dec[g] + bhh_dec[g]) : (bih_enc[g] + bhh_enc[g]);
    }

    const float xgv = xgv_n;
    if (s < 255) {  // prefetch next step's xg (independent of recurrence)
      const int sn = s + 1;
      xgv_n = xg[(size_t)(((sn >> 7) << 12) + (b << 7) + (sn & 127)) * 1024 + g];
    }

    // full-k dot: h2[rb] reads are wave-uniform (broadcast, conflict-free)
    float a0 = 0.f, a1 = 0.f, a2 = 0.f, a3 = 0.f;
#pragma unroll
    for (int c = 0; c < 23; ++c) {
      const uint4 hv = *(const uint4*)&h2[rb][c << 2];
      a0 = fdot2u(wqd[4 * c + 0], hv.x, a0);
      a1 = fdot2u(wqd[4 * c + 1], hv.y, a1);
      a2 = fdot2u(wqd[4 * c + 2], hv.z, a2);
      a3 = fdot2u(wqd[4 * c + 3], hv.w, a3);
    }
#pragma unroll
    for (int c = 23; c < 32; ++c) {
      const uint4 hv = *(const uint4*)&h2[rb][c << 2];
      const int dp0 = (4 * c - 92) >> 1;  // 0,2,4,...,16
      const uint2 w01 = *(const uint2*)&WL[(dp0 << 11) + (t << 1)];
      const uint2 w23 = *(const uint2*)&WL[((dp0 + 1) << 11) + (t << 1)];
      a0 = fdot2u(w01.x, hv.x, a0);
      a1 = fdot2u(w01.y, hv.y, a1);
      a2 = fdot2u(w23.x, hv.z, a2);
      a3 = fdot2u(w23.y, hv.w, a3);
    }
    const float accf = bias_g + xgv + ((a0 + a1) + (a2 + a3));

    // branchless activation: act = s*sigmoid(s*x) - (s-1)  (s=2 -> tanh, s=1 -> sigmoid)
    const float e = __expf(-s_act * accf);
    const float act = fmaf(s_act, 1.f / (1.f + e), o_act);

    // in-quad combine: 3 shuffles give every lane (i,f,g,o) of its unit
    const float pv = __shfl_xor(act, 1, 64);
    const float lo = (qc & 1) ? pv : act;   // pair's even-role gate (i or g)
    const float hi = (qc & 1) ? act : pv;   // pair's odd-role gate  (f or o)
    const float lo2 = __shfl_xor(lo, 2, 64);
    const float hi2 = __shfl_xor(hi, 2, 64);
    const bool m2 = (qc & 2) != 0;
    const float iv = m2 ? lo2 : lo;
    const float fv = m2 ? hi2 : hi;
    const float gv = m2 ? lo : lo2;
    const float ov = m2 ? hi : hi2;

    c_r = fv * c_r + iv * gv;
    const float hh = ov * tanh_fast(c_r);
    if (p && qc == 0) decO[(size_t)((b << 7) + tt) * 256 + u] = f2bf_bits(hh);
    const float hn = __shfl_down(hh, 4, 64);  // hh of unit u+1 (lane +4, stays in-wave)
    if ((t & 7) == 0)
      h2[rb ^ 1][t >> 3] = (unsigned)f2h_bits(hh) | ((unsigned)f2h_bits(hn) << 16);
    __syncthreads();  // write-buffer h2[rb^1] complete before next step reads it
  }
}

// ---------------------------------------------------------------- proj ----
// out[m][n] = sum_k A[m][k]*Bw[n][k] + bias[n];  M=4096 N=32000 K=256, bf16 MFMA.
// N-strip persistent: WG owns 64 vocab rows. B staged once; B-frags hoisted to regs.
// M-loop: 128 chunks x 32 rows, double-buffered A, counted vmcnt(2).
// Epilogue: acc -> Ol[32][66] (bank-padded) -> wave-coalesced float4 stores
// (16 lanes x 16 B = 256 B contiguous per instruction, full cache lines).
__global__ __launch_bounds__(256, 2) void proj_kernel(
    const unsigned short* __restrict__ A,   // decO bf16 [4096][256]
    const unsigned short* __restrict__ Bw,  // WoutB bf16 [32000][256]
    const float* __restrict__ bias, float* __restrict__ out) {
  __shared__ unsigned short Bl[64 * 256];       // 32 KB
  __shared__ unsigned short Al[2][32 * 256];    // 2 x 16 KB
  __shared__ float Ol[32][66];                  // 8.25 KB, +2 pad breaks 4-way conflicts
  const int n0 = blockIdx.x << 6;     // 0..499 -> vocab row base
  const int tid = threadIdx.x;
  const int wv = tid >> 6, ln = tid & 63;
  const int wm = wv & 1;              // M-half of the 32-row chunk (16 rows)
  const int wn = wv >> 1;             // N-half of the 64-row strip (32 cols)
  const int l16 = ln & 15, lq = ln >> 4;

  // stage B strip (once): slot st -> (n = st>>5, k8 = st&31), source k8 ^ (n&15)
#pragma unroll
  for (int it = 0; it < 8; ++it) {
    int st = it * 256 + tid;
    int m = st >> 5, k8 = st & 31;
    gload_lds16(Bw + (size_t)(n0 + m) * 256 + ((k8 ^ (m & 15)) << 3), &Bl[st << 3]);
  }
  // stage A chunk 0
#pragma unroll
  for (int it = 0; it < 4; ++it) {
    int st = it * 256 + tid;
    int m = st >> 5, k8 = st & 31;
    gload_lds16(A + (size_t)m * 256 + ((k8 ^ (m & 15)) << 3), &Al[0][st << 3]);
  }
  asm volatile("s_waitcnt vmcnt(0)" ::: "memory");
  __syncthreads();

  // hoist B fragments into registers: bfr[nt][ks], reused for all 128 chunks
  bf16x8 bfr[2][8];
#pragma unroll
  for (int nt = 0; nt < 2; ++nt)
#pragma unroll
    for (int ks = 0; ks < 8; ++ks) {
      int n = (wn << 5) + (nt << 4) + l16;
      int k8 = (ks << 2) + lq;
      bfr[nt][ks] = *(const bf16x8*)&Bl[((n << 5) | (k8 ^ (n & 15))) << 3];
    }
  const int gc0 = (wn << 5) + l16;    // col within strip
  const float bs0 = bias[n0 + gc0];
  const float bs1 = bias[n0 + gc0 + 16];

  for (int c = 0; c < 128; ++c) {
    const int cur = c & 1;
    if (c < 127) {  // issue next A chunk (4 gload_lds) before compute
      const unsigned short* Ab = A + (size_t)(c + 1) * (32 * 256);
#pragma unroll
      for (int it = 0; it < 4; ++it) {
        int st = it * 256 + tid;
        int m = st >> 5, k8 = st & 31;
        gload_lds16(Ab + (size_t)m * 256 + ((k8 ^ (m & 15)) << 3), &Al[cur ^ 1][st << 3]);
      }
    }

    f32x4 acc0 = {}, acc1 = {};
#pragma unroll
    for (int ks = 0; ks < 8; ++ks) {
      const int k8 = (ks << 2) + lq;
      const int m = (wm << 4) + l16;
      const bf16x8 af = *(const bf16x8*)&Al[cur][((m << 5) | (k8 ^ (m & 15))) << 3];
      acc0 = __builtin_amdgcn_mfma_f32_16x16x32_bf16(af, bfr[0][ks], acc0, 0, 0, 0);
      acc1 = __builtin_amdgcn_mfma_f32_16x16x32_bf16(af, bfr[1][ks], acc1, 0, 0, 0);
    }

    // stage chunk result to LDS (bias fused); 2 lanes/bank = free
    const int orow = (wm << 4) + (lq << 2);
#pragma unroll
    for (int rr = 0; rr < 4; ++rr) {
      Ol[orow + rr][gc0] = acc0[rr] + bs0;
      Ol[orow + rr][gc0 + 16] = acc1[rr] + bs1;
    }
    __syncthreads();

    // coalesced store: 16 lanes x float4 = 256 B contiguous per wave-instruction
#pragma unroll
    for (int pp = 0; pp < 2; ++pp) {
      const int r = (pp << 4) + (tid >> 4);
      const int sl = tid & 15;
      const float4 v = *(const float4*)&Ol[r][sl << 2];
      *(float4*)&out[(size_t)((c << 5) + r) * 32000 + n0 + (sl << 2)] = v;
    }

    // drain the 4 A-loads (older than this chunk's 2 stores); stores stay in flight
    asm volatile("s_waitcnt vmcnt(2)" ::: "memory");
    __syncthreads();  // Al[cur^1] visible to all waves; Ol reads done before rewrite
  }
}

// -------------------------------------------------------------- launch ----
extern "C" void kernel_launch(void* const* d_in, const int* in_sizes, int n_in,
                              void* d_out, int out_size, void* d_ws, size_t ws_size,
                              hipStream_t stream) {
  const int* x = (const int*)d_in[0];
  const int* y = (const int*)d_in[1];
  const float* enc_emb = (const float*)d_in[2];
  const float* dec_emb = (const float*)d_in[3];
  const float* Wih_enc = (const float*)d_in[4];
  const float* Whh_enc = (const float*)d_in[5];
  const float* bih_enc = (const float*)d_in[6];
  const float* bhh_enc = (const float*)d_in[7];
  const float* Wih_dec = (const float*)d_in[8];
  const float* Whh_dec = (const float*)d_in[9];
  const float* bih_dec = (const float*)d_in[10];
  const float* bhh_dec = (const float*)d_in[11];
  const float* W_out = (const float*)d_in[12];
  const float* b_out = (const float*)d_in[13];

  char* ws = (char*)d_ws;
  float* xg = (float*)ws;                                       // 33,554,432
  unsigned* WhhP = (unsigned*)(ws + 33554432);                  //  1,048,576
  unsigned short* WoutB = (unsigned short*)(ws + 34603008);     // 16,384,000
  unsigned short* decO = (unsigned short*)(ws + 50987008);      //  2,097,152
  if (ws_size < 57344000) return;  // insufficient workspace (would corrupt)

  prep_kernel<<<4096, 256, 0, stream>>>(Whh_enc, Whh_dec, W_out, WhhP, WoutB);
  xg_kernel<<<dim3(16, 128), 256, 0, stream>>>(x, y, enc_emb, dec_emb, Wih_enc, Wih_dec, xg);
  lstm_kernel<<<32, 1024, 0, stream>>>(xg, WhhP, bih_enc, bhh_enc, bih_dec, bhh_dec, decO);
  proj_kernel<<<500, 256, 0, stream>>>(decO, WoutB, b_out, (float*)d_out);
}